// Round 4
// baseline (223.051 us; speedup 1.0000x reference)
//
#include <hip/hip_runtime.h>

#define N 8192
#define NCLS 81
#define PAD 300
#define NPANEL 16
#define PANW 512
#define ROWW 128   // u64 words per mask row (row-major, 1KB rows)
#define JSPLIT 8

typedef unsigned long long u64;

// ---------------- K1: decode + argmax pick + key pack + rank zero ----------------
__global__ __launch_bounds__(256) void decode_kernel(
    const float* __restrict__ meta, const float* __restrict__ deltas,
    const float* __restrict__ proposals, const float* __restrict__ scores,
    float4* __restrict__ sel, u64* __restrict__ keys, int* __restrict__ rank) {
  int row = blockIdx.x * blockDim.x + threadIdx.x;
  if (row >= N) return;
  float H = meta[0], W = meta[1], sc = meta[2];
  const float* p = proposals + row * 4;
  float x1 = p[0] / sc, y1 = p[1] / sc, x2 = p[2] / sc, y2 = p[3] / sc;
  float w = x2 - x1 + 1.0f, h = y2 - y1 + 1.0f;
  float cx = x1 + 0.5f * w, cy = y1 + 0.5f * h;

  const float* s = scores + (size_t)row * NCLS;
  int best = 0;
  float bs = s[0];
  float ms = -1e30f;  // max over classes 1..80
  for (int c = 1; c < NCLS; ++c) {
    float v = s[c];
    if (v > bs) { bs = v; best = c; }  // strict > : first-max, matches jnp.argmax
    ms = fmaxf(ms, v);
  }

  const float* d = deltas + (size_t)row * (4 * NCLS) + best * 4;
  float pcx = d[0] * w + cx;
  float pcy = d[1] * h + cy;
  float pw = expf(d[2]) * w;
  float ph = expf(d[3]) * h;
  float lx = W - 1.0f, ly = H - 1.0f;
  float ox1 = fminf(fmaxf(pcx - 0.5f * pw, 0.0f), lx);
  float oy1 = fminf(fmaxf(pcy - 0.5f * ph, 0.0f), ly);
  float ox2 = fminf(fmaxf(pcx + 0.5f * pw, 0.0f), lx);
  float oy2 = fminf(fmaxf(pcy + 0.5f * ph, 0.0f), ly);
  sel[row] = make_float4(ox1, oy1, ox2, oy2);
  // sort key: (score desc, idx asc) == ascending u64 of (~score_bits)<<32 | idx
  keys[row] = ((u64)(~__float_as_uint(ms)) << 32) | (unsigned int)row;
  rank[row] = 0;
}

// ---------------- K2a: brute-force rank (stable sort of unique keys) ----------------
__global__ __launch_bounds__(256) void rank_kernel(
    const u64* __restrict__ keys, int* __restrict__ rank) {
  int i = blockIdx.x * 256 + threadIdx.x;
  u64 ki = keys[i];
  int j0 = blockIdx.y * (N / JSPLIT);
  int c = 0;
#pragma unroll 8
  for (int j = j0; j < j0 + N / JSPLIT; ++j) c += (keys[j] < ki);
  atomicAdd(&rank[i], c);
}

// ---------------- K2b: scatter into sorted order ----------------
__global__ __launch_bounds__(256) void scatter_kernel(
    const int* __restrict__ rank, const float4* __restrict__ sel,
    int* __restrict__ sortedIdx, float4* __restrict__ sortedBoxes) {
  int i = blockIdx.x * 256 + threadIdx.x;
  int r = rank[i];
  sortedIdx[r] = i;
  sortedBoxes[r] = sel[i];
}

// ---------------- K3: suppression bitmask, row-major, UPPER TRIANGLE ONLY ----------------
// mask[r*128 + cb] bit c set iff j = cb*64+c, j > r, IoU > 0.5. Lower-tri words are
// left as poison: every consumer only reads bits at columns >= current scan position
// (slab poison lands at bits < li; full-row poison lands at words below the next
// panel's broadcast range) — proven never re-read.
__global__ __launch_bounds__(64) void mask_kernel(
    const float4* __restrict__ boxes, u64* __restrict__ mask) {
  int rb = blockIdx.y, cb = blockIdx.x;
  if (cb < rb) return;
  int r = rb * 64 + threadIdx.x;
  __shared__ float4 cbox[64];
  cbox[threadIdx.x] = boxes[cb * 64 + threadIdx.x];
  __syncthreads();
  float4 bi = boxes[r];
  float areaA = fmaxf(bi.z - bi.x, 0.0f) * fmaxf(bi.w - bi.y, 0.0f);
  u64 bits = 0ull;
#pragma unroll 8
  for (int c = 0; c < 64; ++c) {
    int j = cb * 64 + c;
    float4 bj = cbox[c];
    float areaB = fmaxf(bj.z - bj.x, 0.0f) * fmaxf(bj.w - bj.y, 0.0f);
    float lxv = fmaxf(bi.x, bj.x), lyv = fmaxf(bi.y, bj.y);
    float rxv = fminf(bi.z, bj.z), ryv = fminf(bi.w, bj.w);
    float iw = fmaxf(rxv - lxv, 0.0f), ih = fmaxf(ryv - lyv, 0.0f);
    float inter = iw * ih;
    float iou = inter / (areaA + areaB - inter + 1e-8f);
    if (j > r && iou > 0.5f) bits |= (1ull << c);
  }
  mask[(size_t)r * ROWW + cb] = bits;
}

// ---------------- K4: serial greedy scan, register-resident full-width remv ----------------
__global__ __launch_bounds__(64) void nms_scan_kernel(
    const u64* __restrict__ mask, int* __restrict__ kept, int* __restrict__ num_kept) {
  __shared__ u64 slab[PANW * 8];  // 32 KiB: current panel diagonal block
  __shared__ int keptLi[PAD];     // in-panel indices of keeps (this panel's tail used at exit)
  int lane = threadIdx.x;
  u64 own0 = 0ull, own1 = 0ull;   // lane owns remv words 2*lane, 2*lane+1
  int cnt = 0;

  for (int p = 0; p < NPANEL && cnt < PAD; ++p) {
    int base = p * PANW;

    // --- async slab copy: rows [base,base+512) x words [8p,8p+8) -> LDS, 32 x 16B/lane ---
    {
      const char* srcBase = (const char*)(mask + (size_t)base * ROWW + 8 * p);
#pragma unroll
      for (int it = 0; it < 32; ++it) {
        const char* g = srcBase + (size_t)(it * 16 + (lane >> 2)) * (ROWW * 8) + (lane & 3) * 16;
        __builtin_amdgcn_global_load_lds(
            (const __attribute__((address_space(1))) unsigned int*)g,
            (__attribute__((address_space(3))) unsigned int*)(slab + it * 128), 16, 0, 0);
      }
    }

    // --- broadcast current panel's remv words (8p..8p+7) to all lanes ---
    u64 rv[8];
#pragma unroll
    for (int k = 0; k < 8; ++k) {
      u64 v = (k & 1) ? own1 : own0;  // word 8p+k parity == k parity (8p even)
      rv[k] = __shfl(v, 4 * p + (k >> 1));
    }

    __syncthreads();  // drain global_load_lds (vmcnt) + make slab visible

    // --- serial in-panel scan: rv replicated in every lane, no cross-lane in chain ---
    int panelFirst = cnt;
    int li = 0;
    while (cnt < PAD) {
      int wlo = li >> 6;
      int found = -1;
#pragma unroll
      for (int w = 0; w < 8; ++w) {
        if (found < 0 && w >= wlo) {
          u64 v = rv[w];
          if (w == wlo) v |= (1ull << (li & 63)) - 1ull;  // mask bits < li
          u64 inv = ~v;
          if (inv) found = (w << 6) + __ffsll(inv) - 1;
        }
      }
      if (found < 0) break;  // panel exhausted
      li = found;
      int gi = base + li;
      if (lane == 0) kept[cnt] = gi;
      keptLi[cnt] = li;  // all lanes write same value: benign
      cnt++;
      if (cnt >= PAD) break;
      // OR kept row's in-panel segment (64B, LDS broadcast read)
      const ulonglong2* srow = (const ulonglong2*)(slab + li * 8);
#pragma unroll
      for (int k = 0; k < 4; ++k) {
        ulonglong2 v = srow[k];
        rv[2 * k] |= v.x;
        rv[2 * k + 1] |= v.y;
      }
      li++;
      if (li >= PANW) break;
    }
    if (cnt >= PAD) break;  // no future panels -> skip exit fold

    // --- panel exit: fold this panel's keeps' FULL rows into owned remv words ---
    // coalesced: lane reads 16B at row+lane*16 == words 2*lane, 2*lane+1. 8-batched ILP.
    for (int t0 = panelFirst; t0 < cnt; t0 += 8) {
      int m = cnt - t0;
      ulonglong2 v0, v1, v2, v3, v4, v5, v6, v7;
      if (0 < m) v0 = ((const ulonglong2*)(mask + (size_t)(base + keptLi[t0 + 0]) * ROWW))[lane];
      if (1 < m) v1 = ((const ulonglong2*)(mask + (size_t)(base + keptLi[t0 + 1]) * ROWW))[lane];
      if (2 < m) v2 = ((const ulonglong2*)(mask + (size_t)(base + keptLi[t0 + 2]) * ROWW))[lane];
      if (3 < m) v3 = ((const ulonglong2*)(mask + (size_t)(base + keptLi[t0 + 3]) * ROWW))[lane];
      if (4 < m) v4 = ((const ulonglong2*)(mask + (size_t)(base + keptLi[t0 + 4]) * ROWW))[lane];
      if (5 < m) v5 = ((const ulonglong2*)(mask + (size_t)(base + keptLi[t0 + 5]) * ROWW))[lane];
      if (6 < m) v6 = ((const ulonglong2*)(mask + (size_t)(base + keptLi[t0 + 6]) * ROWW))[lane];
      if (7 < m) v7 = ((const ulonglong2*)(mask + (size_t)(base + keptLi[t0 + 7]) * ROWW))[lane];
      if (0 < m) { own0 |= v0.x; own1 |= v0.y; }
      if (1 < m) { own0 |= v1.x; own1 |= v1.y; }
      if (2 < m) { own0 |= v2.x; own1 |= v2.y; }
      if (3 < m) { own0 |= v3.x; own1 |= v3.y; }
      if (4 < m) { own0 |= v4.x; own1 |= v4.y; }
      if (5 < m) { own0 |= v5.x; own1 |= v5.y; }
      if (6 < m) { own0 |= v6.x; own1 |= v6.y; }
      if (7 < m) { own0 |= v7.x; own1 |= v7.y; }
    }
    __syncthreads();  // slab reads done before next panel's async copy overwrites
  }
  if (lane == 0) *num_kept = cnt;
}

// ---------------- K5: gather outputs ----------------
__global__ __launch_bounds__(128) void gather_kernel(
    const int* __restrict__ kept, const int* __restrict__ num_kept_p,
    const int* __restrict__ sortedIdx, const float4* __restrict__ sortedBoxes,
    const float* __restrict__ scores, float* __restrict__ out) {
  int r = blockIdx.x;  // 0..299
  int t = threadIdx.x;
  float* boxes_out = out;             // (300,4)
  float* scores_out = out + PAD * 4;  // (300,81)
  int nk = *num_kept_p;
  bool valid = r < nk;
  int pos = valid ? kept[r] : 0;
  if (t < NCLS) {
    int orig = sortedIdx[pos];
    scores_out[(size_t)r * NCLS + t] = valid ? scores[(size_t)orig * NCLS + t] : 0.0f;
  }
  if (t == 96) {
    float4 b = sortedBoxes[pos];
    if (!valid) b = make_float4(0.f, 0.f, 0.f, 0.f);
    ((float4*)boxes_out)[r] = b;
  }
}

extern "C" void kernel_launch(void* const* d_in, const int* in_sizes, int n_in,
                              void* d_out, int out_size, void* d_ws, size_t ws_size,
                              hipStream_t stream) {
  const float* meta = (const float*)d_in[0];
  const float* deltas = (const float*)d_in[1];
  const float* proposals = (const float*)d_in[2];
  const float* scores = (const float*)d_in[3];
  float* out = (float*)d_out;
  char* ws = (char*)d_ws;

  float4* sel = (float4*)(ws + 0);                         // 131072 B
  u64* keys = (u64*)(ws + 131072);                         // 65536 B
  int* rank = (int*)(ws + 196608);                         // 32768 B
  int* sortedIdx = (int*)(ws + 229376);                    // 32768 B
  float4* sortedBoxes = (float4*)(ws + 262144);            // 131072 B
  int* kept = (int*)(ws + 393216);                         // 1200 B
  int* num_kept = (int*)(ws + 395264);                     // 4 B
  u64* mask = (u64*)(ws + 409600);                         // 8 MiB row-major

  decode_kernel<<<N / 256, 256, 0, stream>>>(meta, deltas, proposals, scores, sel, keys, rank);
  rank_kernel<<<dim3(N / 256, JSPLIT), 256, 0, stream>>>(keys, rank);
  scatter_kernel<<<N / 256, 256, 0, stream>>>(rank, sel, sortedIdx, sortedBoxes);
  mask_kernel<<<dim3(N / 64, N / 64), 64, 0, stream>>>(sortedBoxes, mask);
  nms_scan_kernel<<<1, 64, 0, stream>>>(mask, kept, num_kept);
  gather_kernel<<<PAD, 128, 0, stream>>>(kept, num_kept, sortedIdx, sortedBoxes, scores, out);
}

// Round 5
// 149.305 us; speedup vs baseline: 1.4939x; 1.4939x over previous
//
#include <hip/hip_runtime.h>

#define N 8192
#define NCLS 81
#define PAD 300
#define NPANEL 16
#define PANW 512
#define JSPLIT 8

typedef unsigned long long u64;

// ---------------- K1: decode + argmax pick + key pack + rank zero ----------------
__global__ __launch_bounds__(256) void decode_kernel(
    const float* __restrict__ meta, const float* __restrict__ deltas,
    const float* __restrict__ proposals, const float* __restrict__ scores,
    float4* __restrict__ sel, u64* __restrict__ keys, int* __restrict__ rank) {
  int row = blockIdx.x * blockDim.x + threadIdx.x;
  if (row >= N) return;
  float H = meta[0], W = meta[1], sc = meta[2];
  const float* p = proposals + row * 4;
  float x1 = p[0] / sc, y1 = p[1] / sc, x2 = p[2] / sc, y2 = p[3] / sc;
  float w = x2 - x1 + 1.0f, h = y2 - y1 + 1.0f;
  float cx = x1 + 0.5f * w, cy = y1 + 0.5f * h;

  const float* s = scores + (size_t)row * NCLS;
  int best = 0;
  float bs = s[0];
  float ms = -1e30f;  // max over classes 1..80
  for (int c = 1; c < NCLS; ++c) {
    float v = s[c];
    if (v > bs) { bs = v; best = c; }  // strict > : first-max, matches jnp.argmax
    ms = fmaxf(ms, v);
  }

  const float* d = deltas + (size_t)row * (4 * NCLS) + best * 4;
  float pcx = d[0] * w + cx;
  float pcy = d[1] * h + cy;
  float pw = expf(d[2]) * w;
  float ph = expf(d[3]) * h;
  float lx = W - 1.0f, ly = H - 1.0f;
  float ox1 = fminf(fmaxf(pcx - 0.5f * pw, 0.0f), lx);
  float oy1 = fminf(fmaxf(pcy - 0.5f * ph, 0.0f), ly);
  float ox2 = fminf(fmaxf(pcx + 0.5f * pw, 0.0f), lx);
  float oy2 = fminf(fmaxf(pcy + 0.5f * ph, 0.0f), ly);
  sel[row] = make_float4(ox1, oy1, ox2, oy2);
  keys[row] = ((u64)(~__float_as_uint(ms)) << 32) | (unsigned int)row;
  rank[row] = 0;
}

// ---------------- K2a: brute-force rank (stable sort of unique keys) ----------------
__global__ __launch_bounds__(256) void rank_kernel(
    const u64* __restrict__ keys, int* __restrict__ rank) {
  int i = blockIdx.x * 256 + threadIdx.x;
  u64 ki = keys[i];
  int j0 = blockIdx.y * (N / JSPLIT);
  int c = 0;
#pragma unroll 8
  for (int j = j0; j < j0 + N / JSPLIT; ++j) c += (keys[j] < ki);
  atomicAdd(&rank[i], c);
}

// ---------------- K2b: scatter into sorted order ----------------
__global__ __launch_bounds__(256) void scatter_kernel(
    const int* __restrict__ rank, const float4* __restrict__ sel,
    int* __restrict__ sortedIdx, float4* __restrict__ sortedBoxes) {
  int i = blockIdx.x * 256 + threadIdx.x;
  int r = rank[i];
  sortedIdx[r] = i;
  sortedBoxes[r] = sel[i];
}

// ---------------- K3: suppression bitmask, PANEL-MAJOR, upper triangle only ------
// word for (row r, col-block cb) at mask[((cb>>3)*N + r)*8 + (cb&7)].
// Lower-tri words left as poison: consumers only use bits at columns >= the scan
// position (in-word consumed bits are pre-set; full-row fold poison lands at
// already-passed columns; future-panel words are strictly upper-tri). Safe.
__global__ __launch_bounds__(64) void mask_kernel(
    const float4* __restrict__ boxes, u64* __restrict__ mask) {
  int rb = blockIdx.y, cb = blockIdx.x;
  if (cb < rb) return;
  int r = rb * 64 + threadIdx.x;
  __shared__ float4 cbox[64];
  cbox[threadIdx.x] = boxes[cb * 64 + threadIdx.x];
  __syncthreads();
  float4 bi = boxes[r];
  float areaA = fmaxf(bi.z - bi.x, 0.0f) * fmaxf(bi.w - bi.y, 0.0f);
  u64 bits = 0ull;
#pragma unroll 8
  for (int c = 0; c < 64; ++c) {
    int j = cb * 64 + c;
    float4 bj = cbox[c];
    float areaB = fmaxf(bj.z - bj.x, 0.0f) * fmaxf(bj.w - bj.y, 0.0f);
    float lxv = fmaxf(bi.x, bj.x), lyv = fmaxf(bi.y, bj.y);
    float rxv = fminf(bi.z, bj.z), ryv = fminf(bi.w, bj.w);
    float iw = fmaxf(rxv - lxv, 0.0f), ih = fmaxf(ryv - lyv, 0.0f);
    float inter = iw * ih;
    float iou = inter / (areaA + areaB - inter + 1e-8f);
    if (j > r && iou > 0.5f) bits |= (1ull << c);
  }
  mask[((size_t)(cb >> 3) * N + r) * 8 + (cb & 7)] = bits;
}

// ---------------- K4: serial greedy scan ----------------
// remv: full 8192-bit in registers (lane owns words 2l,2l+1). Per panel: lane also
// holds panel word (lane&7) replicated ("remv"), and all lanes hold a broadcast
// copy "cur" of the CURRENT word with consumed bits set. Find = ffsll(~cur).
__global__ __launch_bounds__(64) void nms_scan_kernel(
    const u64* __restrict__ mask, int* __restrict__ kept, int* __restrict__ num_kept) {
  __shared__ u64 slab[2][PANW * 8];  // 2 x 32 KiB double-buffered diagonal slabs
  __shared__ int keptLi[PAD];        // in-panel indices of this panel's keeps
  int lane = threadIdx.x;
  u64 own0 = 0ull, own1 = 0ull;  // lane owns global remv words 2*lane, 2*lane+1
  int cnt = 0;

  // issue slab copy for panel 0
  {
    const char* srcBase = (const char*)(mask + (size_t)0 * N * 8 + (size_t)0 * 8);
#pragma unroll
    for (int it = 0; it < 32; ++it)
      __builtin_amdgcn_global_load_lds(
          (const __attribute__((address_space(1))) unsigned int*)(srcBase + (it * 64 + lane) * 16),
          (__attribute__((address_space(3))) unsigned int*)(&slab[0][0] + it * 128), 16, 0, 0);
  }

  for (int p = 0; p < NPANEL; ++p) {
    int base = p * PANW;
    const u64* sl = &slab[p & 1][0];
    __syncthreads();  // drain slab copy for panel p (vmcnt0 + lgkm)

    // panel-entry: distribute remv word 8p+(lane&7) to each lane
    int src = 4 * p + ((lane & 7) >> 1);
    u64 a = __shfl(own0, src), b = __shfl(own1, src);
    u64 remv = (lane & 1) ? b : a;
    int w = 0;
    u64 cur = __shfl(remv, 0);  // word 8p, consumed bits will be set as we pass

    // serial in-panel scan
    int panelFirst = cnt;
    while (cnt < PAD) {
      u64 inv = ~cur;
      if (inv == 0ull) {  // word exhausted
        if (++w == 8) break;
        cur = __shfl(remv, w);
        continue;
      }
      int bpos = __ffsll(inv) - 1;
      int li = (w << 6) + bpos;
      if (lane == 0) { kept[cnt] = base + li; }
      keptLi[cnt - panelFirst] = li;  // all lanes same value: benign
      cnt++;
      if (cnt >= PAD) break;
      cur |= (1ull << bpos);  // consume
      const u64* srow = sl + li * 8;
      cur |= srow[w];          // broadcast ds_read_b64
      remv |= srow[lane & 7];  // per-lane ds_read_b64 (8-way broadcast groups)
    }
    if (cnt >= PAD || p == NPANEL - 1) break;

    // issue slab copy for panel p+1 (async; completes under the fold below)
    {
      const char* srcBase = (const char*)(mask + ((size_t)(p + 1) * N + (size_t)(base + PANW)) * 8);
      u64* dst = &slab[(p + 1) & 1][0];
#pragma unroll
      for (int it = 0; it < 32; ++it)
        __builtin_amdgcn_global_load_lds(
            (const __attribute__((address_space(1))) unsigned int*)(srcBase + (it * 64 + lane) * 16),
            (__attribute__((address_space(3))) unsigned int*)(dst + it * 128), 16, 0, 0);
    }

    // panel-exit fold: OR this panel's keeps' FULL rows into owned remv words.
    // panel-major full row: lane covers words 2l,2l+1 -> panel (l>>2), pair (l&3).
    int nk = cnt - panelFirst;
    for (int t0 = 0; t0 < nk; t0 += 8) {
      int m = nk - t0;
      ulonglong2 v0, v1, v2, v3, v4, v5, v6, v7;
#define ROWP(t) ((const ulonglong2*)(mask + ((size_t)(lane >> 2) * N + (size_t)(base + keptLi[t])) * 8) + (lane & 3))
      if (0 < m) v0 = *ROWP(t0 + 0);
      if (1 < m) v1 = *ROWP(t0 + 1);
      if (2 < m) v2 = *ROWP(t0 + 2);
      if (3 < m) v3 = *ROWP(t0 + 3);
      if (4 < m) v4 = *ROWP(t0 + 4);
      if (5 < m) v5 = *ROWP(t0 + 5);
      if (6 < m) v6 = *ROWP(t0 + 6);
      if (7 < m) v7 = *ROWP(t0 + 7);
#undef ROWP
      if (0 < m) { own0 |= v0.x; own1 |= v0.y; }
      if (1 < m) { own0 |= v1.x; own1 |= v1.y; }
      if (2 < m) { own0 |= v2.x; own1 |= v2.y; }
      if (3 < m) { own0 |= v3.x; own1 |= v3.y; }
      if (4 < m) { own0 |= v4.x; own1 |= v4.y; }
      if (5 < m) { own0 |= v5.x; own1 |= v5.y; }
      if (6 < m) { own0 |= v6.x; own1 |= v6.y; }
      if (7 < m) { own0 |= v7.x; own1 |= v7.y; }
    }
  }
  if (lane == 0) *num_kept = cnt;
}

// ---------------- K5: gather outputs ----------------
__global__ __launch_bounds__(128) void gather_kernel(
    const int* __restrict__ kept, const int* __restrict__ num_kept_p,
    const int* __restrict__ sortedIdx, const float4* __restrict__ sortedBoxes,
    const float* __restrict__ scores, float* __restrict__ out) {
  int r = blockIdx.x;  // 0..299
  int t = threadIdx.x;
  float* boxes_out = out;             // (300,4)
  float* scores_out = out + PAD * 4;  // (300,81)
  int nk = *num_kept_p;
  bool valid = r < nk;
  int pos = valid ? kept[r] : 0;
  if (t < NCLS) {
    int orig = sortedIdx[pos];
    scores_out[(size_t)r * NCLS + t] = valid ? scores[(size_t)orig * NCLS + t] : 0.0f;
  }
  if (t == 96) {
    float4 b = sortedBoxes[pos];
    if (!valid) b = make_float4(0.f, 0.f, 0.f, 0.f);
    ((float4*)boxes_out)[r] = b;
  }
}

extern "C" void kernel_launch(void* const* d_in, const int* in_sizes, int n_in,
                              void* d_out, int out_size, void* d_ws, size_t ws_size,
                              hipStream_t stream) {
  const float* meta = (const float*)d_in[0];
  const float* deltas = (const float*)d_in[1];
  const float* proposals = (const float*)d_in[2];
  const float* scores = (const float*)d_in[3];
  float* out = (float*)d_out;
  char* ws = (char*)d_ws;

  float4* sel = (float4*)(ws + 0);               // 131072 B
  u64* keys = (u64*)(ws + 131072);               // 65536 B
  int* rank = (int*)(ws + 196608);               // 32768 B
  int* sortedIdx = (int*)(ws + 229376);          // 32768 B
  float4* sortedBoxes = (float4*)(ws + 262144);  // 131072 B
  int* kept = (int*)(ws + 393216);               // 1200 B
  int* num_kept = (int*)(ws + 395264);           // 4 B
  u64* mask = (u64*)(ws + 409600);               // 8 MiB panel-major

  decode_kernel<<<N / 256, 256, 0, stream>>>(meta, deltas, proposals, scores, sel, keys, rank);
  rank_kernel<<<dim3(N / 256, JSPLIT), 256, 0, stream>>>(keys, rank);
  scatter_kernel<<<N / 256, 256, 0, stream>>>(rank, sel, sortedIdx, sortedBoxes);
  mask_kernel<<<dim3(N / 64, N / 64), 64, 0, stream>>>(sortedBoxes, mask);
  nms_scan_kernel<<<1, 64, 0, stream>>>(mask, kept, num_kept);
  gather_kernel<<<PAD, 128, 0, stream>>>(kept, num_kept, sortedIdx, sortedBoxes, scores, out);
}